// Round 6
// baseline (889.758 us; speedup 1.0000x reference)
//
#include <hip/hip_runtime.h>
#include <math.h>

#define BB 64
#define CC 768
#define NN 1024
#define BS 192
#define EPS 1e-5f
#define LAM 0.01f

typedef float  f32x4  __attribute__((ext_vector_type(4)));
typedef short  bf16x8 __attribute__((ext_vector_type(8)));

__device__ inline unsigned f2bf(float x) {
    unsigned u = __float_as_uint(x);
    u += 0x7fff + ((u >> 16) & 1);   // RNE
    return u >> 16;
}
__device__ inline unsigned pack2(float r, float i) { return f2bf(r) | (f2bf(i) << 16); }
__device__ inline float bflo(unsigned v) { return __uint_as_float(v << 16); }
__device__ inline float bfhi(unsigned v) { return __uint_as_float(v & 0xffff0000u); }

// LDS bank swizzle on float2 index (FFT kernels only): XOR bits 4-5 into 2-3.
__device__ inline int swz(int i) { return i ^ (((i >> 4) & 3) << 2); }

// ---------------------------------------------------------------------------
// Kernel 1: LayerNorm statistics per (b, n). float4-vectorized along n.
// ---------------------------------------------------------------------------
__global__ __launch_bounds__(512) void ln_stats(const float* __restrict__ x,
                                                float* __restrict__ mu,
                                                float* __restrict__ rstd) {
    int tn = threadIdx.x & 63, tc = threadIdx.x >> 6;   // tc: 0..7
    int n = blockIdx.x * 256 + tn * 4, b = blockIdx.y;
    const float* xp = x + (size_t)b * CC * NN + n;
    f32x4 s = (f32x4)0.f, ss = (f32x4)0.f;
    #pragma unroll 4
    for (int c = tc; c < CC; c += 8) {
        f32x4 v = *(const f32x4*)(xp + (size_t)c * NN);
        s += v; ss += v * v;
    }
    __shared__ f32x4 sm[8][64], sq[8][64];
    sm[tc][tn] = s; sq[tc][tn] = ss;
    __syncthreads();
    if (tc == 0) {
        f32x4 S  = sm[0][tn], SS = sq[0][tn];
        #pragma unroll
        for (int i = 1; i < 8; i++) { S += sm[i][tn]; SS += sq[i][tn]; }
        f32x4 m = S * (1.f / 768.f);
        f32x4 r;
        #pragma unroll
        for (int i = 0; i < 4; i++) {
            float var = SS[i] * (1.f / 768.f) - m[i] * m[i];
            r[i] = rsqrtf(var + EPS);
        }
        *(f32x4*)(mu + (size_t)b * NN + n)   = m;
        *(f32x4*)(rstd + (size_t)b * NN + n) = r;
    }
}

// ---------------------------------------------------------------------------
// Kernel 2: LN-apply + 1024-pt radix-4 DIF FFT (n) + 4-pt DFT (q) + 1/64.
// Linear plane stores (no column swizzle: GEMM no longer uses LDS).
// ---------------------------------------------------------------------------
__global__ void fwd_fft(const float* __restrict__ x,
                        const float* __restrict__ mu_, const float* __restrict__ rs_,
                        const float* __restrict__ gamma, const float* __restrict__ beta,
                        unsigned* __restrict__ Xp) {
    __shared__ float2 bufs[4][1024];
    int d = blockIdx.x, b = blockIdx.y, tid = threadIdx.x;

    const float* mp = mu_ + b * NN;
    const float* rp = rs_ + b * NN;
    #pragma unroll
    for (int q = 0; q < 4; q++) {
        int c = q * BS + d;
        float g = gamma[c], be = beta[c];
        const float* xp = x + ((size_t)b * CC + c) * NN;
        #pragma unroll
        for (int k = 0; k < 4; k++) {
            int n = tid + 256 * k;
            float v = (xp[n] - mp[n]) * rp[n] * g + be;
            bufs[q][swz(n)] = make_float2(v, 0.f);
        }
    }
    __syncthreads();

    #pragma unroll
    for (int sL = 0; sL < 4; sL++) {
        const int L = 256 >> (2 * sL);
        int j = tid & (L - 1);
        int base = ((tid - j) << 2) + j;
        float s1, c1;
        __sincosf(-(float)M_PI * 0.5f * (float)j / (float)L, &s1, &c1);
        float c2 = c1 * c1 - s1 * s1, s2 = 2.f * c1 * s1;
        float c3 = c2 * c1 - s2 * s1, s3 = c2 * s1 + s2 * c1;
        #pragma unroll
        for (int q = 0; q < 4; q++) {
            float2 a  = bufs[q][swz(base)];
            float2 bb = bufs[q][swz(base + L)];
            float2 cc = bufs[q][swz(base + 2 * L)];
            float2 dd = bufs[q][swz(base + 3 * L)];
            float t0r = a.x + cc.x, t0i = a.y + cc.y;
            float t1r = a.x - cc.x, t1i = a.y - cc.y;
            float t2r = bb.x + dd.x, t2i = bb.y + dd.y;
            float t3r = bb.x - dd.x, t3i = bb.y - dd.y;
            float X0r = t0r + t2r, X0i = t0i + t2i;
            float X2r = t0r - t2r, X2i = t0i - t2i;
            float X1r = t1r + t3i, X1i = t1i - t3r;
            float X3r = t1r - t3i, X3i = t1i + t3r;
            bufs[q][swz(base)]         = make_float2(X0r, X0i);
            bufs[q][swz(base + L)]     = make_float2(X1r * c1 - X1i * s1, X1r * s1 + X1i * c1);
            bufs[q][swz(base + 2 * L)] = make_float2(X2r * c2 - X2i * s2, X2r * s2 + X2i * c2);
            bufs[q][swz(base + 3 * L)] = make_float2(X3r * c3 - X3i * s3, X3r * s3 + X3i * c3);
        }
        __syncthreads();
    }

    float Xr[4][4], Xi[4][4];
    int i0 = swz(4 * tid);
    #pragma unroll
    for (int q = 0; q < 4; q++) {
        const float4* p = (const float4*)&bufs[q][i0];
        float4 u0 = p[0], u1 = p[1];
        float t0r = u0.x + u1.x, t0i = u0.y + u1.y;
        float t1r = u0.x - u1.x, t1i = u0.y - u1.y;
        float t2r = u0.z + u1.z, t2i = u0.w + u1.w;
        float t3r = u0.z - u1.z, t3i = u0.w - u1.w;
        Xr[q][0] = t0r + t2r; Xi[q][0] = t0i + t2i;
        Xr[q][1] = t1r + t3i; Xi[q][1] = t1i - t3r;
        Xr[q][2] = t0r - t2r; Xi[q][2] = t0i - t2i;
        Xr[q][3] = t1r - t3i; Xi[q][3] = t1i + t3r;
    }
    const float sc = 1.f / 64.f;
    unsigned o0[4], o1[4], o2[4], o3[4];
    #pragma unroll
    for (int m = 0; m < 4; m++) {
        float x0r = Xr[0][m], x0i = Xi[0][m];
        float x1r = Xr[1][m], x1i = Xi[1][m];
        float x2r = Xr[2][m], x2i = Xi[2][m];
        float x3r = Xr[3][m], x3i = Xi[3][m];
        float X0r = x0r + x1r + x2r + x3r, X0i = x0i + x1i + x2i + x3i;
        float X2r = x0r - x1r + x2r - x3r, X2i = x0i - x1i + x2i - x3i;
        float X1r = x0r + x1i - x2r - x3i, X1i = x0i - x1r - x2i + x3r;
        float X3r = x0r - x1i - x2r + x3i, X3i = x0i + x1r - x2i - x3r;
        o0[m] = pack2(X0r * sc, X0i * sc);
        o1[m] = pack2(X1r * sc, X1i * sc);
        o2[m] = pack2(X2r * sc, X2i * sc);
        o3[m] = pack2(X3r * sc, X3i * sc);
    }
    size_t qs = (size_t)BS * NN;
    size_t base = (((size_t)b * 4) * BS + d) * NN + 4 * tid;
    *(uint4*)(Xp + base)          = make_uint4(o0[0], o0[1], o0[2], o0[3]);
    *(uint4*)(Xp + base + qs)     = make_uint4(o1[0], o1[1], o1[2], o1[3]);
    *(uint4*)(Xp + base + 2 * qs) = make_uint4(o2[0], o2[1], o2[2], o2[3]);
    *(uint4*)(Xp + base + 3 * qs) = make_uint4(o3[0], o3[1], o3[2], o3[3]);
}

// ---------------------------------------------------------------------------
// Kernel 2b: one-time B prepack, linear tile [jl=0..127][dd=0..15] dwords.
// j even: (Wr,-Wi), j odd: (Wi,Wr).
// ---------------------------------------------------------------------------
__global__ void pack_b(const float* __restrict__ w, unsigned* __restrict__ Bp) {
    int ch = blockIdx.x, nblk = blockIdx.y, q = blockIdx.z;
    size_t tile = (size_t)((q * 3 + nblk) * 12 + ch);
    const float* wr = w + (size_t)q * BS * BS;
    const float* wi = w + (size_t)(4 + q) * BS * BS;
    for (int r = 0; r < 8; r++) {
        int idx = r * 256 + threadIdx.x;
        int jl = idx & 127, dd = idx >> 7;
        int j = nblk * 128 + jl;
        int h = j >> 1;
        int dg = ch * 16 + dd;
        float Wr = wr[(size_t)dg * BS + h];
        float Wi = wi[(size_t)dg * BS + h];
        unsigned v = (j & 1) ? pack2(Wi, Wr) : pack2(Wr, -Wi);
        Bp[tile * 2048 + jl * 16 + dd] = v;
    }
}

// ---------------------------------------------------------------------------
// Kernel 3: bf16 MFMA GEMM, LDS-free / barrier-free. Fragments are loaded
// DIRECTLY from global (A: 16 dword loads/chunk, 64B-coalesced per quad;
// B: 4 dwordx4 loads/chunk from the L2-resident prepacked tile). Full unroll
// lets the scheduler pipeline next-chunk loads under current MFMAs; waves
// never synchronize. Operand-swapped MFMA, register epilogue.
// ---------------------------------------------------------------------------
template <int ACT>
__global__ __launch_bounds__(256) void gemm_mlp(const unsigned* __restrict__ Ap,
                                                const unsigned* __restrict__ Bp,
                                                const float* __restrict__ bias,
                                                unsigned* __restrict__ Cp) {
    const int mblk = blockIdx.x;
    const int nblk = blockIdx.y;
    const int bq   = blockIdx.z;
    const int q    = bq & 3;
    const int tid  = threadIdx.x;
    const int wave = tid >> 6;
    const int lane = tid & 63;
    const int l15  = lane & 15;
    const int quad = lane >> 4;
    const int wm   = (wave & 1) * 64;
    const int wn   = (wave >> 1) * 64;

    // af[t] dword g = Ap[(bq*BS + ch*16 + quad*4 + g)*NN + mblk*128 + wm + t*16 + l15]
    const unsigned* a_lane = Ap + ((size_t)bq * BS + quad * 4) * NN + mblk * 128 + wm + l15;
    // bfr[t] = uint4 at tile + ch*2048 + (wn + t*16 + l15)*16 + quad*4
    const unsigned* b_lane = Bp + (size_t)((q * 3 + nblk) * 12) * 2048 + (wn + l15) * 16 + quad * 4;

    f32x4 acc[4][4];   // acc[tn][tm]
    #pragma unroll
    for (int i = 0; i < 4; i++)
        #pragma unroll
        for (int j = 0; j < 4; j++)
            acc[i][j] = (f32x4)0.f;

    #pragma unroll
    for (int ch = 0; ch < 12; ch++) {
        const unsigned* ap = a_lane + (size_t)(ch * 16) * NN;
        const unsigned* bp = b_lane + ch * 2048;
        bf16x8 af[4], bfr[4];
        #pragma unroll
        for (int t = 0; t < 4; t++) {
            union { unsigned u[4]; bf16x8 v; } au;
            #pragma unroll
            for (int g = 0; g < 4; g++)
                au.u[g] = ap[(size_t)g * NN + t * 16];
            af[t] = au.v;
            union { uint4 u4; bf16x8 v; } bu;
            bu.u4 = *(const uint4*)(bp + t * 256);
            bfr[t] = bu.v;
        }
        #pragma unroll
        for (int tn = 0; tn < 4; tn++)
            #pragma unroll
            for (int tm = 0; tm < 4; tm++)
                acc[tn][tm] = __builtin_amdgcn_mfma_f32_16x16x32_bf16(bfr[tn], af[tm], acc[tn][tm], 0, 0, 0);
    }

    // epilogue: bias + act + pack in registers; linear plane stores.
    #pragma unroll
    for (int tn = 0; tn < 4; tn++) {
        int jb = wn + tn * 16 + quad * 4;
        int hg = nblk * 64 + (jb >> 1);
        float b0r = bias[q * BS + hg];
        float b0i = bias[768 + q * BS + hg];
        float b1r = bias[q * BS + hg + 1];
        float b1i = bias[768 + q * BS + hg + 1];
        size_t row0 = ((size_t)bq * BS + hg) * NN + mblk * 128;
        #pragma unroll
        for (int tm = 0; tm < 4; tm++) {
            int mcol = wm + tm * 16 + l15;
            f32x4 a = acc[tn][tm];
            float v0 = a[0] + b0r, v1 = a[1] + b0i;
            float v2 = a[2] + b1r, v3 = a[3] + b1i;
            if (ACT == 0) {
                v0 = fmaxf(v0, 0.f); v1 = fmaxf(v1, 0.f);
                v2 = fmaxf(v2, 0.f); v3 = fmaxf(v3, 0.f);
            } else {
                v0 = (v0 > LAM) ? (v0 - LAM) : ((v0 < -LAM) ? (v0 + LAM) : 0.f);
                v1 = (v1 > LAM) ? (v1 - LAM) : ((v1 < -LAM) ? (v1 + LAM) : 0.f);
                v2 = (v2 > LAM) ? (v2 - LAM) : ((v2 < -LAM) ? (v2 + LAM) : 0.f);
                v3 = (v3 > LAM) ? (v3 - LAM) : ((v3 < -LAM) ? (v3 + LAM) : 0.f);
            }
            Cp[row0 + mcol]      = pack2(v0, v1);
            Cp[row0 + NN + mcol] = pack2(v2, v3);
        }
    }
}

// ---------------------------------------------------------------------------
// Kernel 4: inverse q-IDFT + radix-4 DIT IFFT + residual. Linear plane loads.
// ---------------------------------------------------------------------------
__global__ void inv_fft(const float* __restrict__ x,
                        const unsigned* __restrict__ Yp,
                        float* __restrict__ out) {
    __shared__ float2 bufs[4][1024];
    int d = blockIdx.x, b = blockIdx.y, tid = threadIdx.x;

    float Ar[4][4], Ai[4][4];
    size_t qs = (size_t)BS * NN;
    size_t rowb = (((size_t)b * 4) * BS + d) * NN + 4 * tid;
    #pragma unroll
    for (int q = 0; q < 4; q++) {
        uint4 v = *(const uint4*)(Yp + rowb + (size_t)q * qs);
        Ar[q][0] = bflo(v.x); Ai[q][0] = bfhi(v.x);
        Ar[q][1] = bflo(v.y); Ai[q][1] = bfhi(v.y);
        Ar[q][2] = bflo(v.z); Ai[q][2] = bfhi(v.z);
        Ar[q][3] = bflo(v.w); Ai[q][3] = bfhi(v.w);
    }
    #pragma unroll
    for (int m = 0; m < 4; m++) {
        float x0r = Ar[0][m], x0i = Ai[0][m];
        float x1r = Ar[1][m], x1i = Ai[1][m];
        float x2r = Ar[2][m], x2i = Ai[2][m];
        float x3r = Ar[3][m], x3i = Ai[3][m];
        float Y0r = x0r + x1r + x2r + x3r, Y0i = x0i + x1i + x2i + x3i;
        float Y2r = x0r - x1r + x2r - x3r, Y2i = x0i - x1i + x2i - x3i;
        float Y1r = x0r - x1i - x2r + x3i, Y1i = x0i + x1r - x2i - x3r;
        float Y3r = x0r + x1i - x2r - x3i, Y3i = x0i - x1r - x2i + x3r;
        Ar[0][m] = Y0r; Ai[0][m] = Y0i;
        Ar[1][m] = Y1r; Ai[1][m] = Y1i;
        Ar[2][m] = Y2r; Ai[2][m] = Y2i;
        Ar[3][m] = Y3r; Ai[3][m] = Y3i;
    }
    int i0 = swz(4 * tid);
    #pragma unroll
    for (int q = 0; q < 4; q++) {
        float t0r = Ar[q][0] + Ar[q][2], t0i = Ai[q][0] + Ai[q][2];
        float t1r = Ar[q][0] - Ar[q][2], t1i = Ai[q][0] - Ai[q][2];
        float t2r = Ar[q][1] + Ar[q][3], t2i = Ai[q][1] + Ai[q][3];
        float t3r = Ar[q][1] - Ar[q][3], t3i = Ai[q][1] - Ai[q][3];
        float4* p = (float4*)&bufs[q][i0];
        p[0] = make_float4(t0r + t2r, t0i + t2i, t1r - t3i, t1i + t3r);
        p[1] = make_float4(t0r - t2r, t0i - t2i, t1r + t3i, t1i - t3r);
    }
    __syncthreads();

    #pragma unroll
    for (int sL = 0; sL < 4; sL++) {
        const int L = 4 << (2 * sL);
        int j = tid & (L - 1);
        int base = ((tid - j) << 2) + j;
        float s1, c1;
        __sincosf((float)M_PI * 0.5f * (float)j / (float)L, &s1, &c1);
        float c2 = c1 * c1 - s1 * s1, s2 = 2.f * c1 * s1;
        float c3 = c2 * c1 - s2 * s1, s3 = c2 * s1 + s2 * c1;
        #pragma unroll
        for (int q = 0; q < 4; q++) {
            float2 y0 = bufs[q][swz(base)];
            float2 y1 = bufs[q][swz(base + L)];
            float2 y2 = bufs[q][swz(base + 2 * L)];
            float2 y3 = bufs[q][swz(base + 3 * L)];
            float A1r = y1.x * c1 - y1.y * s1, A1i = y1.x * s1 + y1.y * c1;
            float A2r = y2.x * c2 - y2.y * s2, A2i = y2.x * s2 + y2.y * c2;
            float A3r = y3.x * c3 - y3.y * s3, A3i = y3.x * s3 + y3.y * c3;
            float t0r = y0.x + A2r, t0i = y0.y + A2i;
            float t1r = y0.x - A2r, t1i = y0.y - A2i;
            float t2r = A1r + A3r, t2i = A1i + A3i;
            float t3r = A1r - A3r, t3i = A1i - A3i;
            bufs[q][swz(base)]         = make_float2(t0r + t2r, t0i + t2i);
            bufs[q][swz(base + L)]     = make_float2(t1r - t3i, t1i + t3r);
            bufs[q][swz(base + 2 * L)] = make_float2(t0r - t2r, t0i - t2i);
            bufs[q][swz(base + 3 * L)] = make_float2(t1r + t3i, t1i - t3r);
        }
        __syncthreads();
    }

    const float sc = 1.f / 64.f;
    #pragma unroll
    for (int q = 0; q < 4; q++) {
        size_t row = (((size_t)b * 4 + q) * BS + d) * NN;
        const float* xp = x + row;
        #pragma unroll
        for (int k = 0; k < 4; k++) {
            int n = tid + 256 * k;
            out[row + n] = bufs[q][swz(n)].x * sc + xp[n];
        }
    }
}

// ---------------------------------------------------------------------------
extern "C" void kernel_launch(void* const* d_in, const int* in_sizes, int n_in,
                              void* d_out, int out_size, void* d_ws, size_t ws_size,
                              hipStream_t stream) {
    const float* x     = (const float*)d_in[0];
    const float* w1    = (const float*)d_in[1];
    const float* w2    = (const float*)d_in[2];
    const float* b1    = (const float*)d_in[3];
    const float* b2    = (const float*)d_in[4];
    const float* gamma = (const float*)d_in[5];
    const float* beta  = (const float*)d_in[6];

    unsigned* Xp = (unsigned*)d_ws;
    float* mu    = (float*)d_ws + (size_t)BB * CC * NN;
    float* rstd  = mu + (size_t)BB * NN;
    unsigned* Bp1 = (unsigned*)(rstd + (size_t)BB * NN);
    unsigned* Bp2 = Bp1 + (size_t)4 * 3 * 12 * 2048;
    unsigned* Hp = (unsigned*)d_out;
    unsigned* Yp = Xp;

    pack_b<<<dim3(12, 3, 4), 256, 0, stream>>>(w1, Bp1);
    pack_b<<<dim3(12, 3, 4), 256, 0, stream>>>(w2, Bp2);
    ln_stats<<<dim3(NN / 256, BB), 512, 0, stream>>>(x, mu, rstd);
    fwd_fft<<<dim3(BS, BB), 256, 0, stream>>>(x, mu, rstd, gamma, beta, Xp);
    gemm_mlp<0><<<dim3(8, 3, 256), 256, 0, stream>>>(Xp, Bp1, b1, Hp);
    gemm_mlp<1><<<dim3(8, 3, 256), 256, 0, stream>>>(Hp, Bp2, b2, Yp);
    inv_fft<<<dim3(BS, BB), 256, 0, stream>>>(x, Yp, (float*)d_out);
}

// Round 7
// 751.204 us; speedup vs baseline: 1.1844x; 1.1844x over previous
//
#include <hip/hip_runtime.h>
#include <math.h>

#define BB 64
#define CC 768
#define NN 1024
#define BS 192
#define EPS 1e-5f
#define LAM 0.01f

typedef float  f32x4  __attribute__((ext_vector_type(4)));
typedef short  bf16x8 __attribute__((ext_vector_type(8)));

__device__ inline unsigned f2bf(float x) {
    unsigned u = __float_as_uint(x);
    u += 0x7fff + ((u >> 16) & 1);   // RNE
    return u >> 16;
}
__device__ inline unsigned pack2(float r, float i) { return f2bf(r) | (f2bf(i) << 16); }
__device__ inline float bflo(unsigned v) { return __uint_as_float(v << 16); }
__device__ inline float bfhi(unsigned v) { return __uint_as_float(v & 0xffff0000u); }

// LDS bank swizzle on float2 index (FFT kernels only): XOR bits 4-5 into 2-3.
__device__ inline int swz(int i) { return i ^ (((i >> 4) & 3) << 2); }

// ---------------------------------------------------------------------------
// Kernel 1: LayerNorm statistics per (b, n). float4-vectorized along n.
// ---------------------------------------------------------------------------
__global__ __launch_bounds__(512) void ln_stats(const float* __restrict__ x,
                                                float* __restrict__ mu,
                                                float* __restrict__ rstd) {
    int tn = threadIdx.x & 63, tc = threadIdx.x >> 6;   // tc: 0..7
    int n = blockIdx.x * 256 + tn * 4, b = blockIdx.y;
    const float* xp = x + (size_t)b * CC * NN + n;
    f32x4 s = (f32x4)0.f, ss = (f32x4)0.f;
    #pragma unroll 4
    for (int c = tc; c < CC; c += 8) {
        f32x4 v = *(const f32x4*)(xp + (size_t)c * NN);
        s += v; ss += v * v;
    }
    __shared__ f32x4 sm[8][64], sq[8][64];
    sm[tc][tn] = s; sq[tc][tn] = ss;
    __syncthreads();
    if (tc == 0) {
        f32x4 S  = sm[0][tn], SS = sq[0][tn];
        #pragma unroll
        for (int i = 1; i < 8; i++) { S += sm[i][tn]; SS += sq[i][tn]; }
        f32x4 m = S * (1.f / 768.f);
        f32x4 r;
        #pragma unroll
        for (int i = 0; i < 4; i++) {
            float var = SS[i] * (1.f / 768.f) - m[i] * m[i];
            r[i] = rsqrtf(var + EPS);
        }
        *(f32x4*)(mu + (size_t)b * NN + n)   = m;
        *(f32x4*)(rstd + (size_t)b * NN + n) = r;
    }
}

// ---------------------------------------------------------------------------
// Kernel 2: LN-apply + 1024-pt radix-4 DIF FFT (n) + 4-pt DFT (q) + 1/64.
// Linear plane stores.
// ---------------------------------------------------------------------------
__global__ void fwd_fft(const float* __restrict__ x,
                        const float* __restrict__ mu_, const float* __restrict__ rs_,
                        const float* __restrict__ gamma, const float* __restrict__ beta,
                        unsigned* __restrict__ Xp) {
    __shared__ float2 bufs[4][1024];
    int d = blockIdx.x, b = blockIdx.y, tid = threadIdx.x;

    const float* mp = mu_ + b * NN;
    const float* rp = rs_ + b * NN;
    #pragma unroll
    for (int q = 0; q < 4; q++) {
        int c = q * BS + d;
        float g = gamma[c], be = beta[c];
        const float* xp = x + ((size_t)b * CC + c) * NN;
        #pragma unroll
        for (int k = 0; k < 4; k++) {
            int n = tid + 256 * k;
            float v = (xp[n] - mp[n]) * rp[n] * g + be;
            bufs[q][swz(n)] = make_float2(v, 0.f);
        }
    }
    __syncthreads();

    #pragma unroll
    for (int sL = 0; sL < 4; sL++) {
        const int L = 256 >> (2 * sL);
        int j = tid & (L - 1);
        int base = ((tid - j) << 2) + j;
        float s1, c1;
        __sincosf(-(float)M_PI * 0.5f * (float)j / (float)L, &s1, &c1);
        float c2 = c1 * c1 - s1 * s1, s2 = 2.f * c1 * s1;
        float c3 = c2 * c1 - s2 * s1, s3 = c2 * s1 + s2 * c1;
        #pragma unroll
        for (int q = 0; q < 4; q++) {
            float2 a  = bufs[q][swz(base)];
            float2 bb = bufs[q][swz(base + L)];
            float2 cc = bufs[q][swz(base + 2 * L)];
            float2 dd = bufs[q][swz(base + 3 * L)];
            float t0r = a.x + cc.x, t0i = a.y + cc.y;
            float t1r = a.x - cc.x, t1i = a.y - cc.y;
            float t2r = bb.x + dd.x, t2i = bb.y + dd.y;
            float t3r = bb.x - dd.x, t3i = bb.y - dd.y;
            float X0r = t0r + t2r, X0i = t0i + t2i;
            float X2r = t0r - t2r, X2i = t0i - t2i;
            float X1r = t1r + t3i, X1i = t1i - t3r;
            float X3r = t1r - t3i, X3i = t1i + t3r;
            bufs[q][swz(base)]         = make_float2(X0r, X0i);
            bufs[q][swz(base + L)]     = make_float2(X1r * c1 - X1i * s1, X1r * s1 + X1i * c1);
            bufs[q][swz(base + 2 * L)] = make_float2(X2r * c2 - X2i * s2, X2r * s2 + X2i * c2);
            bufs[q][swz(base + 3 * L)] = make_float2(X3r * c3 - X3i * s3, X3r * s3 + X3i * c3);
        }
        __syncthreads();
    }

    float Xr[4][4], Xi[4][4];
    int i0 = swz(4 * tid);
    #pragma unroll
    for (int q = 0; q < 4; q++) {
        const float4* p = (const float4*)&bufs[q][i0];
        float4 u0 = p[0], u1 = p[1];
        float t0r = u0.x + u1.x, t0i = u0.y + u1.y;
        float t1r = u0.x - u1.x, t1i = u0.y - u1.y;
        float t2r = u0.z + u1.z, t2i = u0.w + u1.w;
        float t3r = u0.z - u1.z, t3i = u0.w - u1.w;
        Xr[q][0] = t0r + t2r; Xi[q][0] = t0i + t2i;
        Xr[q][1] = t1r + t3i; Xi[q][1] = t1i - t3r;
        Xr[q][2] = t0r - t2r; Xi[q][2] = t0i - t2i;
        Xr[q][3] = t1r - t3i; Xi[q][3] = t1i + t3r;
    }
    const float sc = 1.f / 64.f;
    unsigned o0[4], o1[4], o2[4], o3[4];
    #pragma unroll
    for (int m = 0; m < 4; m++) {
        float x0r = Xr[0][m], x0i = Xi[0][m];
        float x1r = Xr[1][m], x1i = Xi[1][m];
        float x2r = Xr[2][m], x2i = Xi[2][m];
        float x3r = Xr[3][m], x3i = Xi[3][m];
        float X0r = x0r + x1r + x2r + x3r, X0i = x0i + x1i + x2i + x3i;
        float X2r = x0r - x1r + x2r - x3r, X2i = x0i - x1i + x2i - x3i;
        float X1r = x0r + x1i - x2r - x3i, X1i = x0i - x1r - x2i + x3r;
        float X3r = x0r - x1i - x2r + x3i, X3i = x0i + x1r - x2i - x3r;
        o0[m] = pack2(X0r * sc, X0i * sc);
        o1[m] = pack2(X1r * sc, X1i * sc);
        o2[m] = pack2(X2r * sc, X2i * sc);
        o3[m] = pack2(X3r * sc, X3i * sc);
    }
    size_t qs = (size_t)BS * NN;
    size_t base = (((size_t)b * 4) * BS + d) * NN + 4 * tid;
    *(uint4*)(Xp + base)          = make_uint4(o0[0], o0[1], o0[2], o0[3]);
    *(uint4*)(Xp + base + qs)     = make_uint4(o1[0], o1[1], o1[2], o1[3]);
    *(uint4*)(Xp + base + 2 * qs) = make_uint4(o2[0], o2[1], o2[2], o2[3]);
    *(uint4*)(Xp + base + 3 * qs) = make_uint4(o3[0], o3[1], o3[2], o3[3]);
}

// ---------------------------------------------------------------------------
// Kernel 2b: one-time B prepack into flat [q][ch][j=384][dd=16] dwords.
// j even: (Wr,-Wi), j odd: (Wi,Wr).
// ---------------------------------------------------------------------------
__global__ void pack_b(const float* __restrict__ w, unsigned* __restrict__ Bp) {
    int ch = blockIdx.x, q = blockIdx.y;
    const float* wr = w + (size_t)q * BS * BS;
    const float* wi = w + (size_t)(4 + q) * BS * BS;
    size_t base = ((size_t)q * 12 + ch) * (384 * 16);
    for (int r = 0; r < 24; r++) {
        int idx = r * 256 + threadIdx.x;       // 0..6143
        int j = idx >> 4, dd = idx & 15;
        int h = j >> 1;
        int dg = ch * 16 + dd;
        float Wr = wr[(size_t)dg * BS + h];
        float Wi = wi[(size_t)dg * BS + h];
        Bp[base + idx] = (j & 1) ? pack2(Wi, Wr) : pack2(Wr, -Wi);
    }
}

// ---------------------------------------------------------------------------
// Kernel 3: FUSED complex MLP (both layers). Per (bq, m-tile-64) block:
//   layer1: A from global planes (scalar dwords, L1-shared across waves),
//           B1 from L2-resident flat prepack (uint4) -> H panel in LDS
//           (192 rows x 64 dwords, stride 68: 2-way banks on write & read).
//   one __syncthreads();
//   layer2: H-frags from LDS, B2 from global -> softshrink -> Y plane stores.
// No per-chunk barriers; H never touches HBM. Operand-swapped MFMA
// (j on quad/reg, m on l15) as verified in R3-R6.
// ---------------------------------------------------------------------------
__global__ __launch_bounds__(512) void fused_mlp(const unsigned* __restrict__ Ap,
                                                 const unsigned* __restrict__ Bp1,
                                                 const unsigned* __restrict__ Bp2,
                                                 const float* __restrict__ b1,
                                                 const float* __restrict__ b2,
                                                 unsigned* __restrict__ Yp) {
    __shared__ unsigned hl[192 * 68];   // H panel, pad 68 dwords/row

    const int mblk = blockIdx.x;   // 0..15 (64 m each)
    const int bq   = blockIdx.y;   // 0..255
    const int q    = bq & 3;
    const int tid  = threadIdx.x;
    const int wave = tid >> 6;     // 0..7, owns j = wave*48 .. +47
    const int lane = tid & 63;
    const int l15  = lane & 15;
    const int quad = lane >> 4;
    const int jw   = wave * 48;

    const unsigned* a_lane = Ap + ((size_t)bq * BS + quad * 4) * NN + mblk * 64 + l15;
    const size_t bstride = 384 * 16;   // dwords per (q,ch) slab
    const unsigned* b1_lane = Bp1 + (size_t)q * 12 * bstride + (jw + l15) * 16 + quad * 4;
    const unsigned* b2_lane = Bp2 + (size_t)q * 12 * bstride + (jw + l15) * 16 + quad * 4;

    f32x4 acc[3][4];   // acc[tn][tm]
    #pragma unroll
    for (int i = 0; i < 3; i++)
        #pragma unroll
        for (int j = 0; j < 4; j++)
            acc[i][j] = (f32x4)0.f;

    // ---- layer 1: K-loop over 12 chunks, no barriers ----
    for (int ch = 0; ch < 12; ch++) {
        const unsigned* ap = a_lane + (size_t)(ch * 16) * NN;
        const unsigned* bp = b1_lane + ch * bstride;
        bf16x8 af[4], bfr[3];
        #pragma unroll
        for (int tm = 0; tm < 4; tm++) {
            union { unsigned u[4]; bf16x8 v; } au;
            #pragma unroll
            for (int g = 0; g < 4; g++)
                au.u[g] = ap[(size_t)g * NN + tm * 16];
            af[tm] = au.v;
        }
        #pragma unroll
        for (int tn = 0; tn < 3; tn++) {
            union { uint4 u4; bf16x8 v; } bu;
            bu.u4 = *(const uint4*)(bp + tn * 256);
            bfr[tn] = bu.v;
        }
        #pragma unroll
        for (int tn = 0; tn < 3; tn++)
            #pragma unroll
            for (int tm = 0; tm < 4; tm++)
                acc[tn][tm] = __builtin_amdgcn_mfma_f32_16x16x32_bf16(bfr[tn], af[tm], acc[tn][tm], 0, 0, 0);
    }

    // ---- epilogue 1: bias + ReLU -> bf16 pack -> H-LDS; re-zero acc ----
    #pragma unroll
    for (int tn = 0; tn < 3; tn++) {
        int hg = wave * 24 + tn * 8 + quad * 2;   // rows hg, hg+1
        float b0r = b1[q * BS + hg];
        float b0i = b1[768 + q * BS + hg];
        float b1r_ = b1[q * BS + hg + 1];
        float b1i_ = b1[768 + q * BS + hg + 1];
        #pragma unroll
        for (int tm = 0; tm < 4; tm++) {
            int c = tm * 16 + l15;
            f32x4 a = acc[tn][tm];
            float v0 = fmaxf(a[0] + b0r, 0.f);
            float v1 = fmaxf(a[1] + b0i, 0.f);
            float v2 = fmaxf(a[2] + b1r_, 0.f);
            float v3 = fmaxf(a[3] + b1i_, 0.f);
            hl[hg * 68 + c]       = pack2(v0, v1);
            hl[(hg + 1) * 68 + c] = pack2(v2, v3);
            acc[tn][tm] = (f32x4)0.f;
        }
    }
    __syncthreads();

    // ---- layer 2: K-loop over H-LDS, no barriers ----
    for (int ch = 0; ch < 12; ch++) {
        const unsigned* bp = b2_lane + ch * bstride;
        bf16x8 af[4], bfr[3];
        #pragma unroll
        for (int tm = 0; tm < 4; tm++) {
            union { unsigned u[4]; bf16x8 v; } au;
            #pragma unroll
            for (int g = 0; g < 4; g++)
                au.u[g] = hl[(ch * 16 + quad * 4 + g) * 68 + tm * 16 + l15];
            af[tm] = au.v;
        }
        #pragma unroll
        for (int tn = 0; tn < 3; tn++) {
            union { uint4 u4; bf16x8 v; } bu;
            bu.u4 = *(const uint4*)(bp + tn * 256);
            bfr[tn] = bu.v;
        }
        #pragma unroll
        for (int tn = 0; tn < 3; tn++)
            #pragma unroll
            for (int tm = 0; tm < 4; tm++)
                acc[tn][tm] = __builtin_amdgcn_mfma_f32_16x16x32_bf16(bfr[tn], af[tm], acc[tn][tm], 0, 0, 0);
    }

    // ---- epilogue 2: bias + softshrink -> Y plane stores ----
    #pragma unroll
    for (int tn = 0; tn < 3; tn++) {
        int hg = wave * 24 + tn * 8 + quad * 2;
        float b0r = b2[q * BS + hg];
        float b0i = b2[768 + q * BS + hg];
        float b1r_ = b2[q * BS + hg + 1];
        float b1i_ = b2[768 + q * BS + hg + 1];
        size_t row0 = ((size_t)bq * BS + hg) * NN + mblk * 64;
        #pragma unroll
        for (int tm = 0; tm < 4; tm++) {
            int mcol = tm * 16 + l15;
            f32x4 a = acc[tn][tm];
            float v0 = a[0] + b0r, v1 = a[1] + b0i;
            float v2 = a[2] + b1r_, v3 = a[3] + b1i_;
            v0 = (v0 > LAM) ? (v0 - LAM) : ((v0 < -LAM) ? (v0 + LAM) : 0.f);
            v1 = (v1 > LAM) ? (v1 - LAM) : ((v1 < -LAM) ? (v1 + LAM) : 0.f);
            v2 = (v2 > LAM) ? (v2 - LAM) : ((v2 < -LAM) ? (v2 + LAM) : 0.f);
            v3 = (v3 > LAM) ? (v3 - LAM) : ((v3 < -LAM) ? (v3 + LAM) : 0.f);
            Yp[row0 + mcol]      = pack2(v0, v1);
            Yp[row0 + NN + mcol] = pack2(v2, v3);
        }
    }
}

// ---------------------------------------------------------------------------
// Kernel 4: inverse q-IDFT + radix-4 DIT IFFT + residual. Linear plane loads.
// ---------------------------------------------------------------------------
__global__ void inv_fft(const float* __restrict__ x,
                        const unsigned* __restrict__ Yp,
                        float* __restrict__ out) {
    __shared__ float2 bufs[4][1024];
    int d = blockIdx.x, b = blockIdx.y, tid = threadIdx.x;

    float Ar[4][4], Ai[4][4];
    size_t qs = (size_t)BS * NN;
    size_t rowb = (((size_t)b * 4) * BS + d) * NN + 4 * tid;
    #pragma unroll
    for (int q = 0; q < 4; q++) {
        uint4 v = *(const uint4*)(Yp + rowb + (size_t)q * qs);
        Ar[q][0] = bflo(v.x); Ai[q][0] = bfhi(v.x);
        Ar[q][1] = bflo(v.y); Ai[q][1] = bfhi(v.y);
        Ar[q][2] = bflo(v.z); Ai[q][2] = bfhi(v.z);
        Ar[q][3] = bflo(v.w); Ai[q][3] = bfhi(v.w);
    }
    #pragma unroll
    for (int m = 0; m < 4; m++) {
        float x0r = Ar[0][m], x0i = Ai[0][m];
        float x1r = Ar[1][m], x1i = Ai[1][m];
        float x2r = Ar[2][m], x2i = Ai[2][m];
        float x3r = Ar[3][m], x3i = Ai[3][m];
        float Y0r = x0r + x1r + x2r + x3r, Y0i = x0i + x1i + x2i + x3i;
        float Y2r = x0r - x1r + x2r - x3r, Y2i = x0i - x1i + x2i - x3i;
        float Y1r = x0r - x1i - x2r + x3i, Y1i = x0i + x1r - x2i - x3r;
        float Y3r = x0r + x1i - x2r - x3i, Y3i = x0i - x1r - x2i + x3r;
        Ar[0][m] = Y0r; Ai[0][m] = Y0i;
        Ar[1][m] = Y1r; Ai[1][m] = Y1i;
        Ar[2][m] = Y2r; Ai[2][m] = Y2i;
        Ar[3][m] = Y3r; Ai[3][m] = Y3i;
    }
    int i0 = swz(4 * tid);
    #pragma unroll
    for (int q = 0; q < 4; q++) {
        float t0r = Ar[q][0] + Ar[q][2], t0i = Ai[q][0] + Ai[q][2];
        float t1r = Ar[q][0] - Ar[q][2], t1i = Ai[q][0] - Ai[q][2];
        float t2r = Ar[q][1] + Ar[q][3], t2i = Ai[q][1] + Ai[q][3];
        float t3r = Ar[q][1] - Ar[q][3], t3i = Ai[q][1] - Ai[q][3];
        float4* p = (float4*)&bufs[q][i0];
        p[0] = make_float4(t0r + t2r, t0i + t2i, t1r - t3i, t1i + t3r);
        p[1] = make_float4(t0r - t2r, t0i - t2i, t1r + t3i, t1i - t3r);
    }
    __syncthreads();

    #pragma unroll
    for (int sL = 0; sL < 4; sL++) {
        const int L = 4 << (2 * sL);
        int j = tid & (L - 1);
        int base = ((tid - j) << 2) + j;
        float s1, c1;
        __sincosf((float)M_PI * 0.5f * (float)j / (float)L, &s1, &c1);
        float c2 = c1 * c1 - s1 * s1, s2 = 2.f * c1 * s1;
        float c3 = c2 * c1 - s2 * s1, s3 = c2 * s1 + s2 * c1;
        #pragma unroll
        for (int q = 0; q < 4; q++) {
            float2 y0 = bufs[q][swz(base)];
            float2 y1 = bufs[q][swz(base + L)];
            float2 y2 = bufs[q][swz(base + 2 * L)];
            float2 y3 = bufs[q][swz(base + 3 * L)];
            float A1r = y1.x * c1 - y1.y * s1, A1i = y1.x * s1 + y1.y * c1;
            float A2r = y2.x * c2 - y2.y * s2, A2i = y2.x * s2 + y2.y * c2;
            float A3r = y3.x * c3 - y3.y * s3, A3i = y3.x * s3 + y3.y * c3;
            float t0r = y0.x + A2r, t0i = y0.y + A2i;
            float t1r = y0.x - A2r, t1i = y0.y - A2i;
            float t2r = A1r + A3r, t2i = A1i + A3i;
            float t3r = A1r - A3r, t3i = A1i - A3i;
            bufs[q][swz(base)]         = make_float2(t0r + t2r, t0i + t2i);
            bufs[q][swz(base + L)]     = make_float2(t1r - t3i, t1i + t3r);
            bufs[q][swz(base + 2 * L)] = make_float2(t0r - t2r, t0i - t2i);
            bufs[q][swz(base + 3 * L)] = make_float2(t1r + t3i, t1i - t3r);
        }
        __syncthreads();
    }

    const float sc = 1.f / 64.f;
    #pragma unroll
    for (int q = 0; q < 4; q++) {
        size_t row = (((size_t)b * 4 + q) * BS + d) * NN;
        const float* xp = x + row;
        #pragma unroll
        for (int k = 0; k < 4; k++) {
            int n = tid + 256 * k;
            out[row + n] = bufs[q][swz(n)].x * sc + xp[n];
        }
    }
}

// ---------------------------------------------------------------------------
extern "C" void kernel_launch(void* const* d_in, const int* in_sizes, int n_in,
                              void* d_out, int out_size, void* d_ws, size_t ws_size,
                              hipStream_t stream) {
    const float* x     = (const float*)d_in[0];
    const float* w1    = (const float*)d_in[1];
    const float* w2    = (const float*)d_in[2];
    const float* b1    = (const float*)d_in[3];
    const float* b2    = (const float*)d_in[4];
    const float* gamma = (const float*)d_in[5];
    const float* beta  = (const float*)d_in[6];

    unsigned* Xp = (unsigned*)d_ws;
    float* mu    = (float*)d_ws + (size_t)BB * CC * NN;
    float* rstd  = mu + (size_t)BB * NN;
    unsigned* Bp1 = (unsigned*)(rstd + (size_t)BB * NN);
    unsigned* Bp2 = Bp1 + (size_t)4 * 12 * 384 * 16;
    unsigned* Yp = Xp;   // layer-2 output overwrites X region (disjoint m-cols per block)

    pack_b<<<dim3(12, 4), 256, 0, stream>>>(w1, Bp1);
    pack_b<<<dim3(12, 4), 256, 0, stream>>>(w2, Bp2);
    ln_stats<<<dim3(NN / 256, BB), 512, 0, stream>>>(x, mu, rstd);
    fwd_fft<<<dim3(BS, BB), 256, 0, stream>>>(x, mu, rstd, gamma, beta, Xp);
    fused_mlp<<<dim3(16, 256), 512, 0, stream>>>(Xp, Bp1, Bp2, b1, b2, Yp);
    inv_fft<<<dim3(BS, BB), 256, 0, stream>>>(x, Yp, (float*)d_out);
}